// Round 1
// baseline (383.996 us; speedup 1.0000x reference)
//
#include <hip/hip_runtime.h>

// out[b,d,m] = (sum_n seg[b,d,n]*Wt[b,m,n]) / (sum_n Wt[b,m,n]),  Wt = W*(W>0.85)
// bs=4, d=16, n=4096. W = 268 MB read once -> memory-bound, floor ~43 us.
// One wave handles 4 rows (m) of one batch; lanes stride over n with float4.
// R=4 rows/wave amortizes the 16 seg float4 loads (seg traffic = 1 B/B of W).

#define N_DIM 4096
#define D_DIM 16
#define THRESH 0.85f
#define ROWS_PER_WAVE 4

__global__ __launch_bounds__(256) void regu_kernel(
    const float* __restrict__ seg,   // [4][16][4096]
    const float* __restrict__ W,     // [4][4096][4096]
    float* __restrict__ out)         // [4][16][4096]
{
    const int lane = threadIdx.x & 63;
    const int wave_in_block = threadIdx.x >> 6;
    const int gwave = blockIdx.x * 4 + wave_in_block;      // 4096 waves total
    const int row_base = gwave * ROWS_PER_WAVE;            // [0, 16384)
    const int b  = row_base >> 12;                         // /4096 (rows per batch)
    const int m0 = row_base & (N_DIM - 1);

    const float* Wp   = W   + ((size_t)b * N_DIM + m0) * N_DIM;
    const float* segp = seg + (size_t)b * D_DIM * N_DIM;

    float acc[ROWS_PER_WAVE][D_DIM];
    float rowsum[ROWS_PER_WAVE];
#pragma unroll
    for (int r = 0; r < ROWS_PER_WAVE; ++r) {
        rowsum[r] = 0.0f;
#pragma unroll
        for (int d = 0; d < D_DIM; ++d) acc[r][d] = 0.0f;
    }

    // lanes cover 256 consecutive n per chunk (lane*4 .. lane*4+3)
    for (int n0 = 0; n0 < N_DIM; n0 += 256) {
        const int idx = n0 + lane * 4;

        float4 w4[ROWS_PER_WAVE];
#pragma unroll
        for (int r = 0; r < ROWS_PER_WAVE; ++r) {
            float4 v = *(const float4*)(Wp + (size_t)r * N_DIM + idx);
            v.x = (v.x > THRESH) ? v.x : 0.0f;
            v.y = (v.y > THRESH) ? v.y : 0.0f;
            v.z = (v.z > THRESH) ? v.z : 0.0f;
            v.w = (v.w > THRESH) ? v.w : 0.0f;
            w4[r] = v;
            rowsum[r] += (v.x + v.y) + (v.z + v.w);
        }

#pragma unroll
        for (int d = 0; d < D_DIM; ++d) {
            const float4 s = *(const float4*)(segp + d * N_DIM + idx);
#pragma unroll
            for (int r = 0; r < ROWS_PER_WAVE; ++r) {
                acc[r][d] += w4[r].x * s.x;
                acc[r][d] += w4[r].y * s.y;
                acc[r][d] += w4[r].z * s.z;
                acc[r][d] += w4[r].w * s.w;
            }
        }
    }

    // 6-step butterfly reduction across the 64 lanes for all 68 partials
#pragma unroll
    for (int r = 0; r < ROWS_PER_WAVE; ++r) {
#pragma unroll
        for (int d = 0; d < D_DIM; ++d) {
            float v = acc[r][d];
#pragma unroll
            for (int off = 1; off < 64; off <<= 1) v += __shfl_xor(v, off, 64);
            acc[r][d] = v;
        }
        float s = rowsum[r];
#pragma unroll
        for (int off = 1; off < 64; off <<= 1) s += __shfl_xor(s, off, 64);
        rowsum[r] = s;
    }

    if (lane == 0) {
#pragma unroll
        for (int r = 0; r < ROWS_PER_WAVE; ++r) {
            const float inv = 1.0f / rowsum[r];
#pragma unroll
            for (int d = 0; d < D_DIM; ++d) {
                out[((size_t)b * D_DIM + d) * N_DIM + (m0 + r)] = acc[r][d] * inv;
            }
        }
    }
}

extern "C" void kernel_launch(void* const* d_in, const int* in_sizes, int n_in,
                              void* d_out, int out_size, void* d_ws, size_t ws_size,
                              hipStream_t stream) {
    const float* seg = (const float*)d_in[0];   // [4,16,64,64] fp32
    const float* W   = (const float*)d_in[1];   // [4,4096,4096] fp32
    float* out = (float*)d_out;                 // [4,16,64,64] fp32

    // 16384 rows total / (4 rows/wave * 4 waves/block) = 1024 blocks
    regu_kernel<<<1024, 256, 0, stream>>>(seg, W, out);
}